// Round 4
// baseline (120.386 us; speedup 1.0000x reference)
//
#include <hip/hip_runtime.h>
#include <hip/hip_bf16.h>
#include <cstdint>

#define BATCH  8192
#define INDIM  1024   // K (elements == bytes in fp8)
#define OUTDIM 2048   // N

typedef float  f32x4   __attribute__((ext_vector_type(4)));
typedef float  f32x16  __attribute__((ext_vector_type(16)));
typedef int    i32x2   __attribute__((ext_vector_type(2)));
typedef int    i32x4   __attribute__((ext_vector_type(4)));
typedef int    i32x8   __attribute__((ext_vector_type(8)));

// pack 4 floats -> 4 fp8 e4m3 bytes (chip-native format; MFMA consumes same)
__device__ __forceinline__ uint32_t pk_fp8x4(float a, float b, float c, float d) {
    uint32_t v = 0;
    v = __builtin_amdgcn_cvt_pk_fp8_f32(a, b, v, false);  // bytes 0,1
    v = __builtin_amdgcn_cvt_pk_fp8_f32(c, d, v, true);   // bytes 2,3
    return v;
}

// async global->LDS, 16B per lane. LDS dest is wave-uniform base + lane*16.
__device__ __forceinline__ void async_copy16(const void* g, void* l) {
    __builtin_amdgcn_global_load_lds(
        (__attribute__((address_space(1))) void*)(g),
        (__attribute__((address_space(3))) void*)(l),
        16, 0, 0);
}

// 16B-pair swizzle key (fp8 row = 64 B = 4 pairs): rows 1,4 apart differ
__device__ __forceinline__ int k4(int r) { return (r ^ (r >> 2)) & 3; }

// ---------------- prep: x (fp32 [B][K]) -> x_fp8 + x_sq ---------------------
// One wave per row, 4 rows per block. xsq exact fp32.
__global__ __launch_bounds__(256) void prep_x(const float* __restrict__ x,
                                              uint8_t* __restrict__ xq8,
                                              float* __restrict__ xsq) {
    const int wave = threadIdx.x >> 6;
    const int lane = threadIdx.x & 63;
    const int row  = blockIdx.x * 4 + wave;
    const f32x4* src = (const f32x4*)(x + (size_t)row * INDIM);
    uint32_t* dst = (uint32_t*)(xq8 + (size_t)row * INDIM);
    float s = 0.f;
#pragma unroll
    for (int w = 0; w < 4; ++w) {
        const f32x4 v = src[lane + w * 64];
        s += v.x * v.x + v.y * v.y + v.z * v.z + v.w * v.w;
        dst[lane + w * 64] = pk_fp8x4(v.x, v.y, v.z, v.w);
    }
#pragma unroll
    for (int off = 32; off > 0; off >>= 1) s += __shfl_down(s, off);
    if (lane == 0) xsq[row] = s;
}

// ------- prep: P (fp32 [K][O]) -> Pt fp8(32*P) [O][K] + psq_part[4][O] ------
// grid (O/32=64, K/256=4). psq partials computed exact from fp32 P.
// P*32 is a power-of-2 scale (exact); epilogue multiplies acc by 1/16
// (2*cross = 2*acc/32 = acc/16).
__global__ __launch_bounds__(256) void prep_p(const float* __restrict__ P,
                                              uint8_t* __restrict__ pt8,
                                              float* __restrict__ psq_part) {
    __shared__ float tile[64][33];
    __shared__ float psums[32];
    const int tid = threadIdx.x;
    const int o0  = blockIdx.x * 32;
    const int k0  = blockIdx.y * 256;
    const int kk  = tid >> 3;         // 0..31 (load row within half-tile)
    const int oq  = tid & 7;          // 0..7  (float4 col group)
    const int so  = tid >> 3;         // 0..31 (store col)
    const int skc = (tid & 7) * 8;    // 0..56 (store k base)
    float a4[4] = {0.f, 0.f, 0.f, 0.f};
    if (tid < 32) psums[tid] = 0.f;
    for (int st = 0; st < 4; ++st) {
        __syncthreads();   // tile reuse guard (st=0: covers psums init)
#pragma unroll
        for (int r2 = 0; r2 < 2; ++r2) {
            const int k = r2 * 32 + kk;
            const float4 v = *(const float4*)(P + (size_t)(k0 + st * 64 + k) * OUTDIM + o0 + oq * 4);
            tile[k][oq * 4 + 0] = v.x;
            tile[k][oq * 4 + 1] = v.y;
            tile[k][oq * 4 + 2] = v.z;
            tile[k][oq * 4 + 3] = v.w;
            a4[0] += v.x * v.x; a4[1] += v.y * v.y;
            a4[2] += v.z * v.z; a4[3] += v.w * v.w;
        }
        __syncthreads();
        i32x2 w;
        w.x = pk_fp8x4(tile[skc + 0][so] * 32.f, tile[skc + 1][so] * 32.f,
                       tile[skc + 2][so] * 32.f, tile[skc + 3][so] * 32.f);
        w.y = pk_fp8x4(tile[skc + 4][so] * 32.f, tile[skc + 5][so] * 32.f,
                       tile[skc + 6][so] * 32.f, tile[skc + 7][so] * 32.f);
        *(i32x2*)(pt8 + (size_t)(o0 + so) * INDIM + k0 + st * 64 + skc) = w;
    }
#pragma unroll
    for (int e = 0; e < 4; ++e) atomicAdd(&psums[oq * 4 + e], a4[e]);
    __syncthreads();
    if (tid < 32) psq_part[(size_t)blockIdx.y * OUTDIM + o0 + tid] = psums[tid];
}

// ---------------- main GEMM + epilogue --------------------------------------
// C[m][n] = (1/16) * sum_k x8[m][k] * p8[n][k] - xsq[m] - psq[n]
// Tile 128x128, BK=64 bytes, 4 waves (2x2); each wave 64x64 via
// MX-scaled MFMA 32x32x64 f8f6f4 (fmt=fp8/fp8, unit E8M0 scales 0x7F).
//
// Double-buffered pipeline, ROLLED loop (R2/R3's fully-unrolled bodies are
// the prime suspect for the container failures — codegen surface removed):
// issue stage(t+1) into buf^1 BEFORE consuming buf, one __syncthreads() per
// iter. The syncthreads' vmcnt(0) drain lands AFTER the iter's ds_read+MFMA
// have covered the global->LDS latency, instead of serializing before them.
//
// LDS 16B-pair p_lds holds global pair p_g = p_lds ^ k4(r).
#define TM 128
#define TN 128
#define BKB 64

__global__ __launch_bounds__(256) void gemm_ep(const uint8_t* __restrict__ xq8,
                                               const uint8_t* __restrict__ pt8,
                                               const float* __restrict__ xsq,
                                               const float* __restrict__ psq_part,
                                               float* __restrict__ out) {
    __shared__ __align__(16) uint8_t As[2][TM * BKB];   // 2 x 8 KB
    __shared__ __align__(16) uint8_t Bs[2][TN * BKB];   // 2 x 8 KB

    const int tid  = threadIdx.x;
    const int m0   = blockIdx.x * TM;   // 64 blocks
    const int n0   = blockIdx.y * TN;   // 16 blocks
    const int wave = tid >> 6;
    const int lane = tid & 63;
    const int wm   = (wave >> 1) * 64;
    const int wn   = (wave & 1) * 64;
    const int l31  = lane & 31;
    const int half = lane >> 5;

    // per-thread staging geometry (invariant across iters)
    const int sr0 = tid >> 2;                 // slot0 row (0..63)
    const int sq0 = (tid & 3) ^ k4(sr0);      // slot0 global 16B pair
    const int sr1 = sr0 + 64;                 // slot1 row (64..127)
    const int sq1 = (tid & 3) ^ k4(sr1);      // slot1 global 16B pair

    f32x16 acc[2][2];
#pragma unroll
    for (int i = 0; i < 2; ++i)
#pragma unroll
        for (int j = 0; j < 2; ++j)
#pragma unroll
            for (int e = 0; e < 16; ++e) acc[i][j][e] = 0.f;

    // prologue: fill buf 0 with K-block 0
    async_copy16(xq8 + (size_t)(m0 + sr0) * INDIM + sq0 * 16, &As[0][tid * 16]);
    async_copy16(pt8 + (size_t)(n0 + sr0) * INDIM + sq0 * 16, &Bs[0][tid * 16]);
    async_copy16(xq8 + (size_t)(m0 + sr1) * INDIM + sq1 * 16, &As[0][(256 + tid) * 16]);
    async_copy16(pt8 + (size_t)(n0 + sr1) * INDIM + sq1 * 16, &Bs[0][(256 + tid) * 16]);
    __syncthreads();

    int cur = 0;
    for (int kb = 0; kb < INDIM; kb += BKB) {
        // issue next tile's loads first — they drain under this tile's compute
        if (kb + BKB < INDIM) {
            const int nxt = cur ^ 1;
            const int kn  = kb + BKB;
            async_copy16(xq8 + (size_t)(m0 + sr0) * INDIM + kn + sq0 * 16, &As[nxt][tid * 16]);
            async_copy16(pt8 + (size_t)(n0 + sr0) * INDIM + kn + sq0 * 16, &Bs[nxt][tid * 16]);
            async_copy16(xq8 + (size_t)(m0 + sr1) * INDIM + kn + sq1 * 16, &As[nxt][(256 + tid) * 16]);
            async_copy16(pt8 + (size_t)(n0 + sr1) * INDIM + kn + sq1 * 16, &Bs[nxt][(256 + tid) * 16]);
        }

        // load full 32B K-fragment per operand (global chunks 2h, 2h+1)
        i32x8 av[2], bv[2];
#pragma unroll
        for (int i = 0; i < 2; ++i) {
            const int r = wm + i * 32 + l31;
            const uint8_t* base = &As[cur][r * BKB];
            const i32x4 lo = *(const i32x4*)(base + (((half << 1) | 0) ^ k4(r)) * 16);
            const i32x4 hi = *(const i32x4*)(base + (((half << 1) | 1) ^ k4(r)) * 16);
            av[i] = __builtin_shufflevector(lo, hi, 0, 1, 2, 3, 4, 5, 6, 7);
        }
#pragma unroll
        for (int j = 0; j < 2; ++j) {
            const int r = wn + j * 32 + l31;
            const uint8_t* base = &Bs[cur][r * BKB];
            const i32x4 lo = *(const i32x4*)(base + (((half << 1) | 0) ^ k4(r)) * 16);
            const i32x4 hi = *(const i32x4*)(base + (((half << 1) | 1) ^ k4(r)) * 16);
            bv[j] = __builtin_shufflevector(lo, hi, 0, 1, 2, 3, 4, 5, 6, 7);
        }
#pragma unroll
        for (int i = 0; i < 2; ++i)
#pragma unroll
            for (int j = 0; j < 2; ++j)
                acc[i][j] = __builtin_amdgcn_mfma_scale_f32_32x32x64_f8f6f4(
                    av[i], bv[j], acc[i][j],
                    0 /*A fmt: fp8 e4m3*/, 0 /*B fmt: fp8 e4m3*/,
                    0, 0x7F7F7F7F /*scale_a = 1.0*/,
                    0, 0x7F7F7F7F /*scale_b = 1.0*/);

        // drain prefetch (overlapped with compute above) + guard buffer reuse
        __syncthreads();
        cur ^= 1;
    }

    // epilogue: C/D layout col = lane&31, row = (reg&3) + 8*(reg>>2) + 4*half
    // (shape-determined, dtype-independent — guide §3). scale: 2*cross = acc/16
    const float* xsq_w = xsq + m0 + wm;
    float ps[2];
#pragma unroll
    for (int j = 0; j < 2; ++j) {
        const int n = n0 + wn + j * 32 + l31;
        ps[j] = psq_part[n] + psq_part[OUTDIM + n] +
                psq_part[2 * OUTDIM + n] + psq_part[3 * OUTDIM + n];
    }
#pragma unroll
    for (int i = 0; i < 2; ++i) {
#pragma unroll
        for (int rg = 0; rg < 16; ++rg) {
            const int rloc = (rg & 3) + 8 * (rg >> 2) + 4 * half;
            const float xs = xsq_w[i * 32 + rloc];
            float* orow = out + (size_t)(m0 + wm + i * 32 + rloc) * OUTDIM + n0 + wn + l31;
#pragma unroll
            for (int j = 0; j < 2; ++j)
                orow[j * 32] = 0.0625f * acc[i][j][rg] - xs - ps[j];
        }
    }
}

// ---------------- fallback (only if workspace is too small) -----------------
__global__ void fallback_kernel(const float* __restrict__ x,
                                const float* __restrict__ P,
                                float* __restrict__ out) {
    const int o = blockIdx.x * blockDim.x + threadIdx.x;
    const int b = blockIdx.y;
    float cr = 0.f, xq = 0.f, pq = 0.f;
    for (int i = 0; i < INDIM; ++i) {
        const float xv = x[(size_t)b * INDIM + i];
        const float pv = P[(size_t)i * OUTDIM + o];
        cr += xv * pv; xq += xv * xv; pq += pv * pv;
    }
    out[(size_t)b * OUTDIM + o] = 2.f * cr - xq - pq;
}

extern "C" void kernel_launch(void* const* d_in, const int* in_sizes, int n_in,
                              void* d_out, int out_size, void* d_ws, size_t ws_size,
                              hipStream_t stream) {
    (void)in_sizes; (void)n_in; (void)out_size;
    const float* x = (const float*)d_in[0];
    const float* P = (const float*)d_in[1];
    float* out = (float*)d_out;

    const size_t xq_bytes  = (size_t)BATCH * INDIM;        // 8 MB
    const size_t pt_bytes  = (size_t)OUTDIM * INDIM;       // 2 MB
    const size_t xsq_bytes = (size_t)BATCH * 4;            // 32 KB
    const size_t psq_bytes = (size_t)4 * OUTDIM * 4;       // 32 KB
    const size_t need = xq_bytes + pt_bytes + xsq_bytes + psq_bytes;

    if (ws_size < need) {
        fallback_kernel<<<dim3(OUTDIM / 256, BATCH), 256, 0, stream>>>(x, P, out);
        return;
    }

    uint8_t* xq8      = (uint8_t*)d_ws;
    uint8_t* pt8      = (uint8_t*)d_ws + xq_bytes;
    float*   xsq      = (float*)((char*)d_ws + xq_bytes + pt_bytes);
    float*   psq_part = xsq + BATCH;

    prep_x<<<BATCH / 4, 256, 0, stream>>>(x, xq8, xsq);
    prep_p<<<dim3(OUTDIM / 32, INDIM / 256), 256, 0, stream>>>(P, pt8, psq_part);
    gemm_ep<<<dim3(BATCH / TM, OUTDIM / TN), 256, 0, stream>>>(xq8, pt8, xsq, psq_part, out);
}

// Round 5
// 117.779 us; speedup vs baseline: 1.0221x; 1.0221x over previous
//
#include <hip/hip_runtime.h>
#include <hip/hip_bf16.h>
#include <cstdint>

#define BATCH  8192
#define INDIM  1024   // K (elements == bytes in fp8)
#define OUTDIM 2048   // N

typedef float  f32x4   __attribute__((ext_vector_type(4)));
typedef float  f32x16  __attribute__((ext_vector_type(16)));
typedef int    i32x2   __attribute__((ext_vector_type(2)));
typedef int    i32x4   __attribute__((ext_vector_type(4)));
typedef int    i32x8   __attribute__((ext_vector_type(8)));

// pack 4 floats -> 4 fp8 e4m3 bytes (chip-native format; MFMA consumes same)
__device__ __forceinline__ uint32_t pk_fp8x4(float a, float b, float c, float d) {
    uint32_t v = 0;
    v = __builtin_amdgcn_cvt_pk_fp8_f32(a, b, v, false);  // bytes 0,1
    v = __builtin_amdgcn_cvt_pk_fp8_f32(c, d, v, true);   // bytes 2,3
    return v;
}

// async global->LDS, 16B per lane. LDS dest is wave-uniform base + lane*16.
__device__ __forceinline__ void async_copy16(const void* g, void* l) {
    __builtin_amdgcn_global_load_lds(
        (__attribute__((address_space(1))) void*)(g),
        (__attribute__((address_space(3))) void*)(l),
        16, 0, 0);
}

// 16B-pair swizzle key (fp8 row = 64 B = 4 pairs): rows 1,4 apart differ
__device__ __forceinline__ int k4(int r) { return (r ^ (r >> 2)) & 3; }

// ---------------- prep: x (fp32 [B][K]) -> x_fp8 + x_sq ---------------------
// One wave per row, 4 rows per block. xsq exact fp32.
__global__ __launch_bounds__(256) void prep_x(const float* __restrict__ x,
                                              uint8_t* __restrict__ xq8,
                                              float* __restrict__ xsq) {
    const int wave = threadIdx.x >> 6;
    const int lane = threadIdx.x & 63;
    const int row  = blockIdx.x * 4 + wave;
    const f32x4* src = (const f32x4*)(x + (size_t)row * INDIM);
    uint32_t* dst = (uint32_t*)(xq8 + (size_t)row * INDIM);
    float s = 0.f;
#pragma unroll
    for (int w = 0; w < 4; ++w) {
        const f32x4 v = src[lane + w * 64];
        s += v.x * v.x + v.y * v.y + v.z * v.z + v.w * v.w;
        dst[lane + w * 64] = pk_fp8x4(v.x, v.y, v.z, v.w);
    }
#pragma unroll
    for (int off = 32; off > 0; off >>= 1) s += __shfl_down(s, off);
    if (lane == 0) xsq[row] = s;
}

// ------- prep: P (fp32 [K][O]) -> Pt fp8(32*P) [O][K] + psq_part[4][O] ------
// grid (O/32=64, K/256=4). psq partials computed exact from fp32 P.
// P*32 is a power-of-2 scale (exact); epilogue multiplies acc by 1/16
// (2*cross = 2*acc/32 = acc/16).
__global__ __launch_bounds__(256) void prep_p(const float* __restrict__ P,
                                              uint8_t* __restrict__ pt8,
                                              float* __restrict__ psq_part) {
    __shared__ float tile[64][33];
    __shared__ float psums[32];
    const int tid = threadIdx.x;
    const int o0  = blockIdx.x * 32;
    const int k0  = blockIdx.y * 256;
    const int kk  = tid >> 3;         // 0..31 (load row within half-tile)
    const int oq  = tid & 7;          // 0..7  (float4 col group)
    const int so  = tid >> 3;         // 0..31 (store col)
    const int skc = (tid & 7) * 8;    // 0..56 (store k base)
    float a4[4] = {0.f, 0.f, 0.f, 0.f};
    if (tid < 32) psums[tid] = 0.f;
    for (int st = 0; st < 4; ++st) {
        __syncthreads();   // tile reuse guard (st=0: covers psums init)
#pragma unroll
        for (int r2 = 0; r2 < 2; ++r2) {
            const int k = r2 * 32 + kk;
            const float4 v = *(const float4*)(P + (size_t)(k0 + st * 64 + k) * OUTDIM + o0 + oq * 4);
            tile[k][oq * 4 + 0] = v.x;
            tile[k][oq * 4 + 1] = v.y;
            tile[k][oq * 4 + 2] = v.z;
            tile[k][oq * 4 + 3] = v.w;
            a4[0] += v.x * v.x; a4[1] += v.y * v.y;
            a4[2] += v.z * v.z; a4[3] += v.w * v.w;
        }
        __syncthreads();
        i32x2 w;
        w.x = pk_fp8x4(tile[skc + 0][so] * 32.f, tile[skc + 1][so] * 32.f,
                       tile[skc + 2][so] * 32.f, tile[skc + 3][so] * 32.f);
        w.y = pk_fp8x4(tile[skc + 4][so] * 32.f, tile[skc + 5][so] * 32.f,
                       tile[skc + 6][so] * 32.f, tile[skc + 7][so] * 32.f);
        *(i32x2*)(pt8 + (size_t)(o0 + so) * INDIM + k0 + st * 64 + skc) = w;
    }
#pragma unroll
    for (int e = 0; e < 4; ++e) atomicAdd(&psums[oq * 4 + e], a4[e]);
    __syncthreads();
    if (tid < 32) psq_part[(size_t)blockIdx.y * OUTDIM + o0 + tid] = psums[tid];
}

// ---------------- main GEMM + epilogue --------------------------------------
// C[m][n] = (1/16) * sum_k x8[m][k] * p8[n][k] - xsq[m] - psq[n]
//
// 256x256 tile, BK=64 bytes, 8 waves (2m x 4n), 512 threads; wave = 128x64
// output via 4x2 frags of MX-scaled MFMA 32x32x64 f8f6f4 (unit E8M0 scales).
// Rationale (R4 post-mortem): gemm is panel-refetch-bound, not latency-bound
// (dbuf A/B was null). 256^2 halves staging traffic (268->134 MB) and raises
// LDS intensity (12 ds_reads per 8 MFMAs vs 8 per 4). Grid = 256 blocks =
// exactly 1/CU. XCD-aware swizzle (nwg%8==0, bijective): each XCD owns one
// n-column -> its 256KB B-slice L2-resident, A-panels stream once per XCD.
//
// Rolled dbuf loop + __syncthreads (known-good R4 skeleton; full unroll was
// the container-killer in R2/R3). LDS 16B-pair p_lds holds global pair
// p_g = p_lds ^ k4(r).
#define TM 256
#define TN 256
#define BKB 64

__global__ __launch_bounds__(512, 2) void gemm_ep(const uint8_t* __restrict__ xq8,
                                                  const uint8_t* __restrict__ pt8,
                                                  const float* __restrict__ xsq,
                                                  const float* __restrict__ psq_part,
                                                  float* __restrict__ out) {
    __shared__ __align__(16) uint8_t As[2][TM * BKB];   // 2 x 16 KB
    __shared__ __align__(16) uint8_t Bs[2][TN * BKB];   // 2 x 16 KB

    const int tid  = threadIdx.x;
    // XCD swizzle: consecutive hw blockIdx round-robin over 8 XCDs; give each
    // XCD one full n-column (32 m-blocks) so B-slice stays in its L2.
    const int nb   = blockIdx.x & 7;    // n-block 0..7
    const int mb   = blockIdx.x >> 3;   // m-block 0..31
    const int m0   = mb * TM;
    const int n0   = nb * TN;
    const int wave = tid >> 6;          // 0..7
    const int lane = tid & 63;
    const int wm   = (wave >> 2) * 128; // 2 wave-rows
    const int wn   = (wave & 3) * 64;   // 4 wave-cols
    const int l31  = lane & 31;
    const int half = lane >> 5;

    // per-thread staging geometry (invariant across iters): 1024 slots per
    // matrix per buffer, 512 threads -> 2 slots each
    const int sr0 = tid >> 2;                 // slot0 row (0..127)
    const int sq0 = (tid & 3) ^ k4(sr0);      // slot0 global 16B pair
    const int sr1 = sr0 + 128;                // slot1 row (128..255)
    const int sq1 = (tid & 3) ^ k4(sr1);      // slot1 global 16B pair

    f32x16 acc[4][2];
#pragma unroll
    for (int i = 0; i < 4; ++i)
#pragma unroll
        for (int j = 0; j < 2; ++j)
#pragma unroll
            for (int e = 0; e < 16; ++e) acc[i][j][e] = 0.f;

    // prologue: fill buf 0 with K-block 0
    async_copy16(xq8 + (size_t)(m0 + sr0) * INDIM + sq0 * 16, &As[0][tid * 16]);
    async_copy16(pt8 + (size_t)(n0 + sr0) * INDIM + sq0 * 16, &Bs[0][tid * 16]);
    async_copy16(xq8 + (size_t)(m0 + sr1) * INDIM + sq1 * 16, &As[0][(512 + tid) * 16]);
    async_copy16(pt8 + (size_t)(n0 + sr1) * INDIM + sq1 * 16, &Bs[0][(512 + tid) * 16]);
    __syncthreads();

    int cur = 0;
    for (int kb = 0; kb < INDIM; kb += BKB) {
        // issue next tile's loads first — they drain under this tile's compute
        if (kb + BKB < INDIM) {
            const int nxt = cur ^ 1;
            const int kn  = kb + BKB;
            async_copy16(xq8 + (size_t)(m0 + sr0) * INDIM + kn + sq0 * 16, &As[nxt][tid * 16]);
            async_copy16(pt8 + (size_t)(n0 + sr0) * INDIM + kn + sq0 * 16, &Bs[nxt][tid * 16]);
            async_copy16(xq8 + (size_t)(m0 + sr1) * INDIM + kn + sq1 * 16, &As[nxt][(512 + tid) * 16]);
            async_copy16(pt8 + (size_t)(n0 + sr1) * INDIM + kn + sq1 * 16, &Bs[nxt][(512 + tid) * 16]);
        }

        // load full 32B K-fragment per operand (global chunks 2h, 2h+1)
        i32x8 av[4], bv[2];
#pragma unroll
        for (int i = 0; i < 4; ++i) {
            const int r = wm + i * 32 + l31;
            const uint8_t* base = &As[cur][r * BKB];
            const i32x4 lo = *(const i32x4*)(base + (((half << 1) | 0) ^ k4(r)) * 16);
            const i32x4 hi = *(const i32x4*)(base + (((half << 1) | 1) ^ k4(r)) * 16);
            av[i] = __builtin_shufflevector(lo, hi, 0, 1, 2, 3, 4, 5, 6, 7);
        }
#pragma unroll
        for (int j = 0; j < 2; ++j) {
            const int r = wn + j * 32 + l31;
            const uint8_t* base = &Bs[cur][r * BKB];
            const i32x4 lo = *(const i32x4*)(base + (((half << 1) | 0) ^ k4(r)) * 16);
            const i32x4 hi = *(const i32x4*)(base + (((half << 1) | 1) ^ k4(r)) * 16);
            bv[j] = __builtin_shufflevector(lo, hi, 0, 1, 2, 3, 4, 5, 6, 7);
        }
#pragma unroll
        for (int i = 0; i < 4; ++i)
#pragma unroll
            for (int j = 0; j < 2; ++j)
                acc[i][j] = __builtin_amdgcn_mfma_scale_f32_32x32x64_f8f6f4(
                    av[i], bv[j], acc[i][j],
                    0 /*A fmt: fp8 e4m3*/, 0 /*B fmt: fp8 e4m3*/,
                    0, 0x7F7F7F7F /*scale_a = 1.0*/,
                    0, 0x7F7F7F7F /*scale_b = 1.0*/);

        // drain prefetch (overlapped with compute above) + guard buffer reuse
        __syncthreads();
        cur ^= 1;
    }

    // epilogue: C/D layout col = lane&31, row = (reg&3) + 8*(reg>>2) + 4*half
    // (shape-determined, dtype-independent — guide §3). scale: 2*cross = acc/16
    const float* xsq_w = xsq + m0 + wm;
    float ps[2];
#pragma unroll
    for (int j = 0; j < 2; ++j) {
        const int n = n0 + wn + j * 32 + l31;
        ps[j] = psq_part[n] + psq_part[OUTDIM + n] +
                psq_part[2 * OUTDIM + n] + psq_part[3 * OUTDIM + n];
    }
#pragma unroll
    for (int i = 0; i < 4; ++i) {
#pragma unroll
        for (int rg = 0; rg < 16; ++rg) {
            const int rloc = (rg & 3) + 8 * (rg >> 2) + 4 * half;
            const float xs = xsq_w[i * 32 + rloc];
            float* orow = out + (size_t)(m0 + wm + i * 32 + rloc) * OUTDIM + n0 + wn + l31;
#pragma unroll
            for (int j = 0; j < 2; ++j)
                orow[j * 32] = 0.0625f * acc[i][j][rg] - xs - ps[j];
        }
    }
}

// ---------------- fallback (only if workspace is too small) -----------------
__global__ void fallback_kernel(const float* __restrict__ x,
                                const float* __restrict__ P,
                                float* __restrict__ out) {
    const int o = blockIdx.x * blockDim.x + threadIdx.x;
    const int b = blockIdx.y;
    float cr = 0.f, xq = 0.f, pq = 0.f;
    for (int i = 0; i < INDIM; ++i) {
        const float xv = x[(size_t)b * INDIM + i];
        const float pv = P[(size_t)i * OUTDIM + o];
        cr += xv * pv; xq += xv * xv; pq += pv * pv;
    }
    out[(size_t)b * OUTDIM + o] = 2.f * cr - xq - pq;
}

extern "C" void kernel_launch(void* const* d_in, const int* in_sizes, int n_in,
                              void* d_out, int out_size, void* d_ws, size_t ws_size,
                              hipStream_t stream) {
    (void)in_sizes; (void)n_in; (void)out_size;
    const float* x = (const float*)d_in[0];
    const float* P = (const float*)d_in[1];
    float* out = (float*)d_out;

    const size_t xq_bytes  = (size_t)BATCH * INDIM;        // 8 MB
    const size_t pt_bytes  = (size_t)OUTDIM * INDIM;       // 2 MB
    const size_t xsq_bytes = (size_t)BATCH * 4;            // 32 KB
    const size_t psq_bytes = (size_t)4 * OUTDIM * 4;       // 32 KB
    const size_t need = xq_bytes + pt_bytes + xsq_bytes + psq_bytes;

    if (ws_size < need) {
        fallback_kernel<<<dim3(OUTDIM / 256, BATCH), 256, 0, stream>>>(x, P, out);
        return;
    }

    uint8_t* xq8      = (uint8_t*)d_ws;
    uint8_t* pt8      = (uint8_t*)d_ws + xq_bytes;
    float*   xsq      = (float*)((char*)d_ws + xq_bytes + pt_bytes);
    float*   psq_part = xsq + BATCH;

    prep_x<<<BATCH / 4, 256, 0, stream>>>(x, xq8, xsq);
    prep_p<<<dim3(OUTDIM / 32, INDIM / 256), 256, 0, stream>>>(P, pt8, psq_part);
    gemm_ep<<<(BATCH / TM) * (OUTDIM / TN), 512, 0, stream>>>(xq8, pt8, xsq, psq_part, out);
}